// Round 4
// baseline (75.563 us; speedup 1.0000x reference)
//
#include <hip/hip_runtime.h>

#define V 96
#define VV (V * V)
#define V3 (V * V * V)
#define B_ 4
#define N_ 32
#define P_ 32
#define NE (N_ * P_)              // 1024 edges per batch element
#define TILE 64                   // pixels per block (one per lane)
#define TPB 1024
#define NW (TPB / 64)             // 16 waves = poly-split factor
#define TILES_PER_B (VV / TILE)   // 144

// ---------------------------------------------------------------------------
// Prologue: build per-edge structs in workspace (128 KB).
// Edge e (global, 0..4095) -> 8 floats: {x0, y0, ex, ey, rq, ry, y1, pad}
// Wave-uniform consumers read these via scalar loads (SMEM pipe), so the
// main kernel's inner loop touches neither LDS nor VMEM.
// ---------------------------------------------------------------------------
__global__ __launch_bounds__(256) void edge_kernel(
    const float* __restrict__ poly,      // (B,N,P,2)
    float4* __restrict__ es)             // 4096 * 2 float4
{
    const int e = blockIdx.x * 256 + threadIdx.x;            // 0..4095
    const float2* p2 = (const float2*)poly;
    const int en = (e & ~(P_ - 1)) | ((e + 1) & (P_ - 1));   // wrap in polygon
    float2 v0 = p2[e];
    float2 v1 = p2[en];
    float ex = v1.x - v0.x, ey = v1.y - v0.y;
    es[e * 2]     = make_float4(v0.x, v0.y, ex, ey);
    es[e * 2 + 1] = make_float4(__builtin_amdgcn_rcpf(ex * ex + ey * ey + 1e-8f),
                                __builtin_amdgcn_rcpf(ey + 1e-8f),
                                v1.y,          // exact next-vertex y
                                0.0f);
}

// ---------------------------------------------------------------------------
// Main fused kernel: 16-wave blocks (TPB=1024) -> 2 blocks/CU = 32 waves/CU
// (full occupancy; launch_bounds forces <=64 VGPR). Each block owns 64 px of
// one batch element; wave s handles valid polys j = s, s+16, ...
// Inner loop: edge data via uniform scalar loads (SGPR operands), parity
// accumulated as a wave mask in SGPRs (SALU), ~17 VALU per edge.
// ---------------------------------------------------------------------------
__global__ __launch_bounds__(TPB, 8) void fused_kernel(
    const float* __restrict__ es,        // (B*N*P)*8 floats edge structs
    const float* __restrict__ attr,      // (B,8)
    const float* __restrict__ validity,  // (B,N)
    float4* __restrict__ out)            // (B,V,V,V) viewed as float4
{
    __shared__ float spart[NW][TILE];
    __shared__ __align__(16) float sfinal[TILE];
    __shared__ int svalidIdx[N_];
    __shared__ int scnt;

    const int b       = blockIdx.x / TILES_PER_B;
    const int tileInB = blockIdx.x - b * TILES_PER_B;
    const int pix0    = tileInB * TILE;
    const int tid     = threadIdx.x;
    const int s       = tid >> 6;            // wave id = polygon split
    const int lane    = tid & 63;

    // wave 0: compact the valid-polygon list via ballot
    if (tid < 64) {
        bool v = (tid < N_) && (validity[b * N_ + tid] >= 0.5f);
        unsigned long long m = __ballot(v);
        if (v) svalidIdx[__popcll(m & ((1ull << tid) - 1))] = tid;
        if (tid == 0) scnt = (int)__popcll(m);
    }
    __syncthreads();

    // this thread's pixel, exact fp32 coords (match numpy)
    const int pixel = pix0 + lane;
    const int py_i  = pixel / V;
    const int px_i  = pixel - py_i * V;
    const float px = (float)px_i / 95.0f;
    const float py = (float)py_i / 95.0f;

    const int cnt = scnt;
    float pmax = 0.0f;

    for (int j = s; j < cnt; j += NW) {
        const int nidx = __builtin_amdgcn_readfirstlane(svalidIdx[j]);
        const float* E = es + ((size_t)(b * N_ + nidx) << 8);   // poly base (32 edges * 8)

        float mind2 = 1e30f;
        unsigned long long pm = 0ull;             // per-wave parity mask (SGPR pair)
        bool cprev = (E[1] <= py);                // y0 of edge 0 (== y1 of edge 31)

        #pragma unroll 4
        for (int p = 0; p < P_; ++p) {
            const float* e8 = E + (p << 3);       // uniform address -> s_load
            float x0 = e8[0], y0 = e8[1];
            float ex = e8[2], ey = e8[3];
            float rq = e8[4], ry = e8[5];
            float y1 = e8[6];
            // point-to-segment squared distance
            float vx = px - x0, vy = py - y0;
            float t  = (vx * ex + vy * ey) * rq;
            t = __builtin_amdgcn_fmed3f(t, 0.0f, 1.0f);   // clamp [0,1]
            float dx = vx - t * ex, dy = vy - t * ey;
            mind2 = fminf(mind2, dx * dx + dy * dy);
            // even-odd crossing: reuse vertex compare chain (y1_p == y0_{p+1})
            bool cnext = (y1 <= py);
            float ix = x0 + ex * (vy * ry);
            pm ^= (__ballot(cprev != cnext) & __ballot(ix > px));  // SALU parity
            cprev = cnext;
        }
        float mind = sqrtf(mind2);
        bool inside = (pm >> lane) & 1ull;
        float sdf  = inside ? -mind : mind;
        // sigmoid(-sdf*100) = 1/(1+exp(100*sdf))
        float m = 1.0f / (1.0f + __expf(sdf * 100.0f));
        pmax = fmaxf(pmax, m);
    }

    spart[s][lane] = pmax;
    __syncthreads();
    if (tid < 64) {
        float f = spart[0][lane];
        #pragma unroll
        for (int w = 1; w < NW; ++w) f = fmaxf(f, spart[w][lane]);
        sfinal[lane] = f;
    }
    __syncthreads();

    // ---- write phase: 96 depth slices x 16 float4 = 1536 float4 stores ----
    float a  = attr[b * 8];
    float nh = fminf(fmaxf(a, 0.0f), 1.0f);
    float hv = fminf(fmaxf(rintf(nh * (float)V), 1.0f), (float)V); // rintf = numpy half-even
    int hvi = (int)hv;

    const float4* sf4 = (const float4*)sfinal;
    size_t obase = (size_t)b * (V3 / 4) + (size_t)(pix0 >> 2);
    #pragma unroll
    for (int k = 0; k < 2; ++k) {
        int idx = tid + k * TPB;                 // 0..2047, use 0..1535
        if (idx < 1536) {
            int d  = idx >> 4;                   // depth slice 0..95
            int x4 = idx & 15;                   // float4 within the 64-px tile
            float4 val = sf4[x4];
            float keep = (d < hvi) ? 1.0f : 0.0f;
            out[obase + (size_t)d * (VV / 4) + x4] =
                make_float4(val.x * keep, val.y * keep, val.z * keep, val.w * keep);
        }
    }
}

extern "C" void kernel_launch(void* const* d_in, const int* in_sizes, int n_in,
                              void* d_out, int out_size, void* d_ws, size_t ws_size,
                              hipStream_t stream) {
    const float* polygons = (const float*)d_in[0];   // (4,32,32,2)
    const float* attrs    = (const float*)d_in[1];   // (4,8)
    const float* validity = (const float*)d_in[2];   // (4,32)
    float4* out = (float4*)d_out;                    // (4,96,96,96)
    float* es   = (float*)d_ws;                      // 128 KB edge structs

    // workspace is re-poisoned each call -> edge_kernel rewrites all structs
    edge_kernel<<<(B_ * NE) / 256, 256, 0, stream>>>(polygons, (float4*)es);
    fused_kernel<<<B_ * TILES_PER_B, TPB, 0, stream>>>(es, attrs, validity, out);
}